// Round 6
// baseline (778.111 us; speedup 1.0000x reference)
//
#include <hip/hip_runtime.h>
#include <hip/hip_fp16.h>

// Problem constants: B=2, CIN=32, COUT=64, K=9, H=256, W=512, OH=256, OW=512
#define HW_IN   131072
#define W_IN    512
#define H_IN    256
#define HW_OUT  131072
#define CIN     32
#define COUT    64
#define KK      9
#define BB      2

typedef _Float16 hf2 __attribute__((ext_vector_type(2)));
typedef _Float16 hf8 __attribute__((ext_vector_type(8)));
typedef float f32x4 __attribute__((ext_vector_type(4)));

static __device__ __forceinline__ hf8 u4h(uint4 u) {
  return __builtin_bit_cast(hf8, u);
}

// ---------------------------------------------------------------------------
// Kernel 1: direct transpose x (B,CIN,H*W) fp32 -> xt (H*W, B, CIN) f16.
// Thread = (hw, g); stores are fully contiguous 1KB per wave; reads are 8
// plane streams of 32B segments (other halves L1-hit by neighbor wave).
// ---------------------------------------------------------------------------
__global__ __launch_bounds__(256) void transpose_direct(
    const float* __restrict__ x, _Float16* __restrict__ xt) {
  int tid = blockIdx.x * 256 + threadIdx.x;   // [0, 1048576)
  int g   = tid & 7;                          // granule: bc = g*8 + c
  int hw  = tid >> 3;                         // [0, 131072)

  const float* src = x + (size_t)(g * 8) * HW_IN + hw;
  hf8 h;
#pragma unroll
  for (int c = 0; c < 8; ++c) h[c] = (_Float16)src[(size_t)c * HW_IN];
  *(hf8*)(xt + (size_t)hw * 64 + g * 8) = h;
}

// ---------------------------------------------------------------------------
// Kernel 2: fused gather + MFMA contraction, BATCH-PHASED.
// GEMM view: out[b,pix,o] = sum_{ck} samp[b,pix,ck] * W[o,ck].
// One wave = 16 hw x 64 couts; the two batches are processed in two
// SEQUENTIAL passes (#pragma unroll 1) so the device-wide concurrent gather
// working set is the 8 MB b-half of the table instead of all 16 MB ->
// per-XCD L2 hit rate ~25% -> ~50%. (The table record [hw] = [b0|b1] is two
// separate 64B lines, so a b-pass touches only its own lines.)
// Sample coords are preloaded once and reused across both passes.
// A-frag 16x16x32 f16: lane m=lane&15 -> hw, quad=lane>>4 -> channel quarter;
// corner gather = one 64B line per 4-lane set. B-frags from LDS [k][o][c]
// f16 (36KB, conflict-free). Per pass: 9 taps x 4 MFMAs, then 4 float4
// stores (C rows = 4 consecutive hw).
// ---------------------------------------------------------------------------
__global__ __launch_bounds__(256, 4) void mapped_conv_mfma(
    const _Float16* __restrict__ xt,
    const float* __restrict__ weight,   // [COUT][CIN][KK] fp32
    const float* __restrict__ bias,     // [COUT]
    const float* __restrict__ sm,       // [HW_OUT][KK][2] fp32
    float* __restrict__ out) {          // [BB][COUT][HW_OUT] fp32
  __shared__ __align__(16) _Float16 w_lds[KK * COUT * CIN];  // 36 KB

  int t = threadIdx.x;
  // Stage weights: w_lds[(k*64 + o)*32 + c] = W[o][c][k] as f16.
  for (int j = t; j < COUT * CIN * KK; j += 256) {
    unsigned ju = (unsigned)j;
    unsigned o  = ju / 288u;
    unsigned rr = ju % 288u;
    unsigned c  = rr / 9u;
    unsigned k  = rr % 9u;
    w_lds[(k * 64u + o) * 32u + c] = (_Float16)weight[ju];
  }
  __syncthreads();

  int wave = t >> 6;
  int lane = t & 63;
  int m    = lane & 15;   // A-row: hw within tile; B-col: cout within N-tile
  int quad = lane >> 4;   // channel quarter (A) / k-chunk (B) / row group (C)

  int hw_base = blockIdx.x * 64 + wave * 16;      // 2048 blocks x 4 waves
  int hw      = hw_base + m;

  const uint4* xt4 = (const uint4*)xt;

  // Preload all 9 taps' sample coords once (shared across both b passes).
  const float* smp = sm + (size_t)hw * (KK * 2);
  float2 s[KK];
#pragma unroll
  for (int k = 0; k < KK; ++k) s[k] = *(const float2*)(smp + k * 2);

  const uint4* wbl = (const uint4*)w_lds + (size_t)(m * 4 + quad);

#pragma unroll 1
  for (int b = 0; b < BB; ++b) {
    int bq = b * 4 + quad;   // uint4-granule within a pixel's 128B record

    f32x4 acc[4] = {{0.f,0.f,0.f,0.f},{0.f,0.f,0.f,0.f},
                    {0.f,0.f,0.f,0.f},{0.f,0.f,0.f,0.f}};

#pragma unroll
    for (int k = 0; k < KK; ++k) {
      float sx = s[k].x;
      float sy = s[k].y;
      float bxf = floorf(sx), byf = floorf(sy);
      float fx = sx - bxf, fy = sy - byf;
      int ix0 = (int)bxf, iy0 = (int)byf;
      int ix1 = min(ix0 + 1, W_IN - 1);
      int iy1 = min(iy0 + 1, H_IN - 1);
      ix0 = max(min(ix0, W_IN - 1), 0); ix1 = max(ix1, 0);
      iy0 = max(min(iy0, H_IN - 1), 0); iy1 = max(iy1, 0);

      uint4 v00 = xt4[(iy0 * W_IN + ix0) * 8 + bq];
      uint4 v01 = xt4[(iy0 * W_IN + ix1) * 8 + bq];
      uint4 v10 = xt4[(iy1 * W_IN + ix0) * 8 + bq];
      uint4 v11 = xt4[(iy1 * W_IN + ix1) * 8 + bq];

      _Float16 w00 = (_Float16)((1.f - fx) * (1.f - fy));
      _Float16 w01 = (_Float16)(fx * (1.f - fy));
      _Float16 w10 = (_Float16)((1.f - fx) * fy);
      _Float16 w11 = (_Float16)(fx * fy);
      hf8 h00 = {w00, w00, w00, w00, w00, w00, w00, w00};
      hf8 h01 = {w01, w01, w01, w01, w01, w01, w01, w01};
      hf8 h10 = {w10, w10, w10, w10, w10, w10, w10, w10};
      hf8 h11 = {w11, w11, w11, w11, w11, w11, w11, w11};

      hf8 a = h00 * u4h(v00) + h01 * u4h(v01) + h10 * u4h(v10) + h11 * u4h(v11);

      const uint4* wk = wbl + (size_t)k * 256;  // per-k block = 64 o * 4 granules
      hf8 b0 = u4h(wk[0]);
      hf8 b1 = u4h(wk[64]);
      hf8 b2 = u4h(wk[128]);
      hf8 b3 = u4h(wk[192]);

      acc[0] = __builtin_amdgcn_mfma_f32_16x16x32_f16(a, b0, acc[0], 0, 0, 0);
      acc[1] = __builtin_amdgcn_mfma_f32_16x16x32_f16(a, b1, acc[1], 0, 0, 0);
      acc[2] = __builtin_amdgcn_mfma_f32_16x16x32_f16(a, b2, acc[2], 0, 0, 0);
      acc[3] = __builtin_amdgcn_mfma_f32_16x16x32_f16(a, b3, acc[3], 0, 0, 0);
    }

    // Per-pass epilogue: lane writes 4 consecutive hw (rows quad*4..+3).
    int hw0 = hw_base + quad * 4;
#pragma unroll
    for (int nt = 0; nt < 4; ++nt) {
      int n = nt * 16 + m;
      float bn = bias[n];
      float4 v = make_float4(acc[nt][0] + bn, acc[nt][1] + bn,
                             acc[nt][2] + bn, acc[nt][3] + bn);
      float* op = out + (size_t)(b * COUT + n) * HW_OUT + hw0;
      *(float4*)op = v;
    }
  }
}

extern "C" void kernel_launch(void* const* d_in, const int* in_sizes, int n_in,
                              void* d_out, int out_size, void* d_ws, size_t ws_size,
                              hipStream_t stream) {
  const float* x  = (const float*)d_in[0];   // [B][CIN][H*W]
  const float* w  = (const float*)d_in[1];   // [COUT][CIN][KK]
  const float* bs = (const float*)d_in[2];   // [COUT]
  const float* sm = (const float*)d_in[3];   // [OH*OW][KK][2]
  float* out = (float*)d_out;                // [B][COUT][OH*OW]
  _Float16* xt = (_Float16*)d_ws;            // 16 MB scratch: (H*W, B, CIN) f16

  transpose_direct<<<dim3(4096), dim3(256), 0, stream>>>(x, xt);
  mapped_conv_mfma<<<dim3(2048), dim3(256), 0, stream>>>(xt, w, bs, sm, out);
}